// Round 10
// baseline (208.171 us; speedup 1.0000x reference)
//
#include <hip/hip_runtime.h>
#include <hip/hip_bf16.h>

// FeedForwardQuantum: out = relu( (cos(theta)*cos(x@Wmap^T)) @ W1^T + b1 ) @ W2^T + b2
// ALL tensors fp32. Compute path: fp32 -> bf16 MFMA -> fp32 out.
//  kW2: W2 fp32 -> w2b bf16 [768][3072], LINEAR (consumed reg-direct from L2).
//  kP : W1+b1 fp32 -> w1p bf16 [3072][32], wire10 = b1, chunks swizzled by (k&3).
//  kQ : coalesced wave-per-row q kernel (unchanged, passing).
//  kG : r9 skeleton (compiler-inserted waitcnt, proven safe) + ONE-STEP W2 prefetch:
//       b(t+1) chunk loads issued right after main(t)'s consuming MFMA cluster
//       (WAR-on-register => compiler orders & counts waits itself; single 24-VGPR
//       B set). Fixes r9's exposed L2 latency (W2 was issued post-B1, consumed
//       ~400cyc later; now ~1500+cyc prefetch distance). LDS = hs 16 KB only.

typedef __attribute__((ext_vector_type(4))) float f32x4;
typedef __attribute__((ext_vector_type(8))) short bf16x8;

#define F_TOTAL 16384
#define E_DIM   768
#define FFN     3072

static __device__ __forceinline__ unsigned short f2bf(float f) {
    union { float f; unsigned int i; } v; v.f = f;
    unsigned int r = v.i + 0x7FFFu + ((v.i >> 16) & 1u);   // RNE
    return (unsigned short)(r >> 16);
}
static __device__ __forceinline__ unsigned int pkbf(float a, float b) {
    __hip_bfloat162 h2 = __float22bfloat162_rn(float2{a, b});   // a -> low, b -> high
    union { __hip_bfloat162 h; unsigned int u; } v; v.h = h2; return v.u;
}

// ---------------- kW2: W2 fp32 -> bf16, LINEAR ----------------
__global__ __launch_bounds__(384) void kW2(const float* __restrict__ w2,
                                           unsigned short* __restrict__ w2b) {
    const int n = (int)blockIdx.x;        // 768 rows
    const int c = (int)threadIdx.x;       // 384 chunks of 8
    const float4* src = (const float4*)(w2 + (size_t)n * FFN + c * 8);
    float4 a = src[0], b = src[1];
    bf16x8 v;
    v[0] = (short)f2bf(a.x); v[1] = (short)f2bf(a.y);
    v[2] = (short)f2bf(a.z); v[3] = (short)f2bf(a.w);
    v[4] = (short)f2bf(b.x); v[5] = (short)f2bf(b.y);
    v[6] = (short)f2bf(b.z); v[7] = (short)f2bf(b.w);
    *(bf16x8*)(w2b + (size_t)n * FFN + (size_t)c * 8) = v;
}

// ---------------- kP: pack W1 + b1 -> w1p[3072][32] (swizzled) ----------------
__global__ void kP(const float* __restrict__ w1,
                   const float* __restrict__ b1,
                   unsigned short* __restrict__ w1p) {
    int k = blockIdx.x * 256 + threadIdx.x;
    if (k >= FFN) return;
    float r[32];
#pragma unroll
    for (int w = 0; w < 10; ++w) r[w] = w1[k * 10 + w];
    r[10] = b1[k];
#pragma unroll
    for (int w = 11; w < 32; ++w) r[w] = 0.f;
#pragma unroll
    for (int c = 0; c < 4; ++c) {
        bf16x8 v;
#pragma unroll
        for (int e = 0; e < 8; ++e) v[e] = (short)f2bf(r[c * 8 + e]);
        *(bf16x8*)(w1p + (size_t)k * 32 + (size_t)((c ^ (k & 3)) * 8)) = v;
    }
}

// ---------------- kQ: coalesced wave-per-row (unchanged) ----------------------
__global__ __launch_bounds__(256) void kQ(const float* __restrict__ x,
                                          const float* __restrict__ wm,
                                          const float* __restrict__ th,
                                          unsigned short* __restrict__ qp) {
    __shared__ float wms[10 * 768];  // 30 KB
    const int tid = (int)threadIdx.x;
    for (int i = tid; i < 10 * 768; i += 256) wms[i] = wm[i];
    __syncthreads();

    const int wv = tid >> 6, l = tid & 63;
    const int mbase = (int)blockIdx.x * 16 + wv * 4;
    const float thv = (l < 10) ? th[l] : 0.f;
    const float cth = __cosf(thv);

#pragma unroll
    for (int r = 0; r < 4; ++r) {
        const int m = mbase + r;
        const float4* xp = (const float4*)(x + (size_t)m * E_DIM);
        const float4 xa = xp[l], xb = xp[64 + l], xc = xp[128 + l];
        float s[10];
#pragma unroll
        for (int w = 0; w < 10; ++w) {
            const float4* wp = (const float4*)(wms + w * E_DIM);
            const float4 wa = wp[l], wb = wp[64 + l], wc = wp[128 + l];
            float t0 = xa.x * wa.x;
            float t1 = xa.y * wa.y;
            t0 = fmaf(xa.z, wa.z, t0); t1 = fmaf(xa.w, wa.w, t1);
            t0 = fmaf(xb.x, wb.x, t0); t1 = fmaf(xb.y, wb.y, t1);
            t0 = fmaf(xb.z, wb.z, t0); t1 = fmaf(xb.w, wb.w, t1);
            t0 = fmaf(xc.x, wc.x, t0); t1 = fmaf(xc.y, wc.y, t1);
            t0 = fmaf(xc.z, wc.z, t0); t1 = fmaf(xc.w, wc.w, t1);
            s[w] = t0 + t1;
        }
#pragma unroll
        for (int w = 0; w < 10; ++w) {
            float v = s[w];
            v += __shfl_xor(v, 1);  v += __shfl_xor(v, 2);  v += __shfl_xor(v, 4);
            v += __shfl_xor(v, 8);  v += __shfl_xor(v, 16); v += __shfl_xor(v, 32);
            s[w] = v;
        }
        if (l < 32) {
            float sv = 0.f;
#pragma unroll
            for (int w = 0; w < 10; ++w) sv = (l == w) ? s[w] : sv;
            float val = (l < 10) ? (cth * __cosf(sv)) : ((l == 10) ? 1.0f : 0.f);
            qp[(size_t)m * 32 + (size_t)((((l >> 3) ^ (m & 3)) * 8) + (l & 7))] = f2bf(val);
        }
    }
}

// ---------------- kG: fused GEMM, W2 reg-direct + 1-step prefetch -------------
// 512 blocks (128 m-tiles x 4 n-slabs, XCD-grouped by slab), 512 threads (8 waves).
// BM=128, BN=192, BK=64. LDS = hs 16 KiB ONLY, 2 blocks/CU.
// Step t: [B1] -> h(t): 4 swapped MFMA(f,aq) -> relu+pack -> 4 ds_write_b64 ->
//   issue f=W1(t+1) -> [lgkm0; B2] -> main kk2=0 (4 ds_read + 12 MFMA on b0,b2,b4)
//   -> issue b0,b2,b4 = W2(t+1).chunk0 -> kk2=1 (12 MFMA on b1,b3,b5) ->
//   issue b1,b3,b5 = W2(t+1).chunk1.   All waitcnt compiler-derived.
__global__ __launch_bounds__(512, 4) void kG(const unsigned short* __restrict__ w2b,
                                             const float* __restrict__ b2,
                                             const unsigned short* __restrict__ qp,
                                             const unsigned short* __restrict__ w1p,
                                             float* __restrict__ outp) {
    __shared__ __align__(16) unsigned short hs[128 * 64];      // 16 KB, [m][k] swz8

    const int tid = (int)threadIdx.x;
    const int wv = tid >> 6, l = tid & 63;
    const int bid = (int)blockIdx.x;
    const int x8 = bid & 7, yb = bid >> 3;          // 2 XCDs per n-slab
    const int m0 = ((x8 & 1) * 64 + yb) * 128;
    const int n0 = (x8 >> 1) * 192;

    const int wr = wv >> 2, wc = wv & 3;     // main-phase wave tile (2m x 4n)

    // h-write element offsets (swapped layout): lane l holds h[hm][ki*16+(l>>4)*4 ..+3]
    int hwo[4];
    {
        const int hm = wv * 16 + (l & 15);
        const int kb = (l >> 4) * 4;
#pragma unroll
        for (int ki = 0; ki < 4; ++ki) {
            int k = ki * 16 + kb;
            int c = k >> 3;
            hwo[ki] = hm * 64 + ((c ^ (hm & 7)) * 8) + (k & 7);
        }
    }

    // 32-bit element offsets (loop-invariant); bases stay uniform (SGPR)
    unsigned int o2[3];
#pragma unroll
    for (int ni = 0; ni < 3; ++ni)
        o2[ni] = (unsigned int)((n0 + wc * 48 + ni * 16 + (l & 15)) * FFN + (l >> 4) * 8);
    const unsigned int o1 = (unsigned int)((l & 15) * 32 + ((l >> 4) ^ (l & 3)) * 8);

    // ---- prologue: aq, f = W1(0), b = W2(0) ----
    bf16x8 aq = *(const bf16x8*)(qp + (size_t)(m0 + wv * 16 + (l & 15)) * 32
                                    + (size_t)(((l >> 4) ^ (l & 3)) * 8));
    bf16x8 f0 = *(const bf16x8*)(w1p + o1);
    bf16x8 f1 = *(const bf16x8*)(w1p + o1 + 512);
    bf16x8 f2 = *(const bf16x8*)(w1p + o1 + 1024);
    bf16x8 f3 = *(const bf16x8*)(w1p + o1 + 1536);
    bf16x8 b0  = *(const bf16x8*)(w2b + o2[0]);
    bf16x8 b2_ = *(const bf16x8*)(w2b + o2[1]);
    bf16x8 b4_ = *(const bf16x8*)(w2b + o2[2]);
    bf16x8 b1_ = *(const bf16x8*)(w2b + o2[0] + 32);
    bf16x8 b3_ = *(const bf16x8*)(w2b + o2[1] + 32);
    bf16x8 b5_ = *(const bf16x8*)(w2b + o2[2] + 32);

    const f32x4 z4 = {0.f, 0.f, 0.f, 0.f};
    f32x4 acc[4][3];
#pragma unroll
    for (int a = 0; a < 4; ++a)
#pragma unroll
        for (int b = 0; b < 3; ++b) acc[a][b] = z4;

#pragma unroll 1
    for (int t = 0; t < 48; ++t) {
        // B1: main(t-1) hs readers done.
        asm volatile("" ::: "memory");
        __builtin_amdgcn_s_barrier();
        __builtin_amdgcn_sched_barrier(0);

        // ---- h phase (swapped): mfma(W1,q) -> lane holds h[m=l&15][4 consecutive k]
        {
            f32x4 hv0 = __builtin_amdgcn_mfma_f32_16x16x32_bf16(f0, aq, z4, 0, 0, 0);
            f32x4 hv1 = __builtin_amdgcn_mfma_f32_16x16x32_bf16(f1, aq, z4, 0, 0, 0);
            f32x4 hv2 = __builtin_amdgcn_mfma_f32_16x16x32_bf16(f2, aq, z4, 0, 0, 0);
            f32x4 hv3 = __builtin_amdgcn_mfma_f32_16x16x32_bf16(f3, aq, z4, 0, 0, 0);
            uint2 pw;
            pw.x = pkbf(fmaxf(hv0[0], 0.f), fmaxf(hv0[1], 0.f));
            pw.y = pkbf(fmaxf(hv0[2], 0.f), fmaxf(hv0[3], 0.f));
            *(uint2*)(hs + hwo[0]) = pw;
            pw.x = pkbf(fmaxf(hv1[0], 0.f), fmaxf(hv1[1], 0.f));
            pw.y = pkbf(fmaxf(hv1[2], 0.f), fmaxf(hv1[3], 0.f));
            *(uint2*)(hs + hwo[1]) = pw;
            pw.x = pkbf(fmaxf(hv2[0], 0.f), fmaxf(hv2[1], 0.f));
            pw.y = pkbf(fmaxf(hv2[2], 0.f), fmaxf(hv2[3], 0.f));
            *(uint2*)(hs + hwo[2]) = pw;
            pw.x = pkbf(fmaxf(hv3[0], 0.f), fmaxf(hv3[1], 0.f));
            pw.y = pkbf(fmaxf(hv3[2], 0.f), fmaxf(hv3[3], 0.f));
            *(uint2*)(hs + hwo[3]) = pw;
        }

        const unsigned int tn = (t < 47) ? (unsigned int)(t + 1) : 47u;

        // issue f = W1(t+1) (h-MFMAs above were the last readers of f)
        {
            const unsigned short* pn = w1p + o1 + (size_t)tn * 2048;
            f0 = *(const bf16x8*)(pn);
            f1 = *(const bf16x8*)(pn + 512);
            f2 = *(const bf16x8*)(pn + 1024);
            f3 = *(const bf16x8*)(pn + 1536);
        }

        // B2: hs writes visible (LDS-only drain; VMEM flies through).
        asm volatile("s_waitcnt lgkmcnt(0)" ::: "memory");
        __builtin_amdgcn_sched_barrier(0);
        __builtin_amdgcn_s_barrier();
        __builtin_amdgcn_sched_barrier(0);

        const unsigned int tn64 = tn * 64u;

        // ---- main kk2=0: consume b0,b2_,b4_ ----
        {
            const int kc = (l >> 4);
            bf16x8 af[4];
#pragma unroll
            for (int mi = 0; mi < 4; ++mi) {
                int m_ = wr * 64 + mi * 16 + (l & 15);
                af[mi] = *(const bf16x8*)(hs + m_ * 64 + ((kc ^ (m_ & 7)) * 8));
            }
            __builtin_amdgcn_s_setprio(1);
#pragma unroll
            for (int mi = 0; mi < 4; ++mi) {
                acc[mi][0] = __builtin_amdgcn_mfma_f32_16x16x32_bf16(af[mi], b0,  acc[mi][0], 0, 0, 0);
                acc[mi][1] = __builtin_amdgcn_mfma_f32_16x16x32_bf16(af[mi], b2_, acc[mi][1], 0, 0, 0);
                acc[mi][2] = __builtin_amdgcn_mfma_f32_16x16x32_bf16(af[mi], b4_, acc[mi][2], 0, 0, 0);
            }
            __builtin_amdgcn_s_setprio(0);
        }
        // prefetch W2(t+1) chunk0 into the just-freed regs (WAR orders after MFMAs)
        b0  = *(const bf16x8*)(w2b + o2[0] + tn64);
        b2_ = *(const bf16x8*)(w2b + o2[1] + tn64);
        b4_ = *(const bf16x8*)(w2b + o2[2] + tn64);

        // ---- main kk2=1: consume b1_,b3_,b5_ ----
        {
            const int kc = 4 + (l >> 4);
            bf16x8 af[4];
#pragma unroll
            for (int mi = 0; mi < 4; ++mi) {
                int m_ = wr * 64 + mi * 16 + (l & 15);
                af[mi] = *(const bf16x8*)(hs + m_ * 64 + ((kc ^ (m_ & 7)) * 8));
            }
            __builtin_amdgcn_s_setprio(1);
#pragma unroll
            for (int mi = 0; mi < 4; ++mi) {
                acc[mi][0] = __builtin_amdgcn_mfma_f32_16x16x32_bf16(af[mi], b1_, acc[mi][0], 0, 0, 0);
                acc[mi][1] = __builtin_amdgcn_mfma_f32_16x16x32_bf16(af[mi], b3_, acc[mi][1], 0, 0, 0);
                acc[mi][2] = __builtin_amdgcn_mfma_f32_16x16x32_bf16(af[mi], b5_, acc[mi][2], 0, 0, 0);
            }
            __builtin_amdgcn_s_setprio(0);
        }
        // prefetch W2(t+1) chunk1
        b1_ = *(const bf16x8*)(w2b + o2[0] + tn64 + 32);
        b3_ = *(const bf16x8*)(w2b + o2[1] + tn64 + 32);
        b5_ = *(const bf16x8*)(w2b + o2[2] + tn64 + 32);
    }

    // epilogue: + b2, fp32 store
#pragma unroll
    for (int ni = 0; ni < 3; ++ni) {
        int n = n0 + wc * 48 + ni * 16 + (l & 15);
        float b2v = b2[n];
#pragma unroll
        for (int mi = 0; mi < 4; ++mi) {
            int mb = m0 + wr * 64 + mi * 16 + (l >> 4) * 4;
#pragma unroll
            for (int jj = 0; jj < 4; ++jj)
                outp[(size_t)(mb + jj) * E_DIM + n] = acc[mi][ni][jj] + b2v;
        }
    }
}

extern "C" void kernel_launch(void* const* d_in, const int* in_sizes, int n_in,
                              void* d_out, int out_size, void* d_ws, size_t ws_size,
                              hipStream_t stream) {
    const float* x    = (const float*)d_in[0];
    const float* wmap = (const float*)d_in[1];
    const float* th   = (const float*)d_in[2];
    const float* w1   = (const float*)d_in[3];
    const float* b1   = (const float*)d_in[4];
    const float* w2   = (const float*)d_in[5];
    const float* b2   = (const float*)d_in[6];
    float* out = (float*)d_out;

    unsigned short* qp  = (unsigned short*)d_ws;            // 16384*32 bf16 = 1 MiB
    unsigned short* w1p = qp + (size_t)F_TOTAL * 32;        // 3072*32 bf16 = 192 KiB
    unsigned short* w2b = w1p + (size_t)FFN * 32;           // 768*3072 bf16 = 4.5 MiB

    kW2<<<E_DIM, 384, 0, stream>>>(w2, w2b);
    kP<<<(FFN + 255) / 256, 256, 0, stream>>>(w1, b1, w1p);
    kQ<<<1024, 256, 0, stream>>>(x, wmap, th, qp);
    kG<<<512, 512, 0, stream>>>(w2b, b2, qp, w1p, out);
}

// Round 11
// 120.230 us; speedup vs baseline: 1.7314x; 1.7314x over previous
//
#include <hip/hip_runtime.h>
#include <hip/hip_bf16.h>

// FeedForwardQuantum: out = relu( (cos(theta)*cos(x@Wmap^T)) @ W1^T + b1 ) @ W2^T + b2
// ALL tensors fp32. Compute path: fp32 -> bf16 MFMA -> fp32 out.
//  kPre: merged pre-pass (one launch, blocks dispatch in parallel):
//    blocks [0,768)    : W2 fp32 -> w2b bf16 [768][3072], 16B-chunk swizzled by (n&7)
//    blocks [768,780)  : W1+b1 -> w1p bf16 [3072][32], wire10=b1, chunks swz by (k&3)
//    blocks [780,1804) : q = cos(th)*cos(x@Wmap^T) -> qp bf16 [16384][32] swizzled
//  kG  : r7 structure (PROVEN best: BM=128 BN=192 BK=64, 8 waves, w2s dbuf 2x24K +
//        hs 16K = 64KB LDS, 2 blocks/CU, manual B1=vmcnt0 / B2=lgkm0 barriers,
//        swapped h-MFMA, reg W1/q frags, setprio) + wave-staggered K-window order
//        in main phase (wv&1 parity) to split the post-B2 LDS read burst.

typedef __attribute__((ext_vector_type(4))) float f32x4;
typedef __attribute__((ext_vector_type(8))) short bf16x8;

#define F_TOTAL 16384
#define E_DIM   768
#define FFN     3072

static __device__ __forceinline__ unsigned short f2bf(float f) {
    union { float f; unsigned int i; } v; v.f = f;
    unsigned int r = v.i + 0x7FFFu + ((v.i >> 16) & 1u);   // RNE
    return (unsigned short)(r >> 16);
}
static __device__ __forceinline__ unsigned int pkbf(float a, float b) {
    __hip_bfloat162 h2 = __float22bfloat162_rn(float2{a, b});   // a -> low, b -> high
    union { __hip_bfloat162 h; unsigned int u; } v; v.h = h2; return v.u;
}
static __device__ __forceinline__ void gload16(const void* g, void* l) {
    __builtin_amdgcn_global_load_lds((const __attribute__((address_space(1))) unsigned int*)g,
                                     (__attribute__((address_space(3))) unsigned int*)l,
                                     16, 0, 0);
}

// ---------------- kPre: merged W2-convert / W1-pack / q-compute ---------------
__global__ __launch_bounds__(256) void kPre(const float* __restrict__ x,
                                            const float* __restrict__ wm,
                                            const float* __restrict__ th,
                                            const float* __restrict__ w1,
                                            const float* __restrict__ b1,
                                            const float* __restrict__ w2,
                                            unsigned short* __restrict__ w2b,
                                            unsigned short* __restrict__ w1p,
                                            unsigned short* __restrict__ qp) {
    __shared__ float wms[10 * 768];  // 30 KB (used by kQ role only)
    const int bid = (int)blockIdx.x;
    const int tid = (int)threadIdx.x;

    if (bid < 768) {
        // --- W2 row bid -> bf16, chunk-swizzled by (n&7) ---
        const int n = bid;
#pragma unroll
        for (int c0 = 0; c0 < 2; ++c0) {
            int c = tid + c0 * 256;
            if (c < 384) {
                const float4* src = (const float4*)(w2 + (size_t)n * FFN + c * 8);
                float4 a = src[0], b = src[1];
                bf16x8 v;
                v[0] = (short)f2bf(a.x); v[1] = (short)f2bf(a.y);
                v[2] = (short)f2bf(a.z); v[3] = (short)f2bf(a.w);
                v[4] = (short)f2bf(b.x); v[5] = (short)f2bf(b.y);
                v[6] = (short)f2bf(b.z); v[7] = (short)f2bf(b.w);
                *(bf16x8*)(w2b + (size_t)n * FFN + (size_t)(c ^ (n & 7)) * 8) = v;
            }
        }
        return;
    }
    if (bid < 780) {
        // --- W1 + b1 pack ---
        int k = (bid - 768) * 256 + tid;
        if (k < FFN) {
            float r[32];
#pragma unroll
            for (int w = 0; w < 10; ++w) r[w] = w1[k * 10 + w];
            r[10] = b1[k];
#pragma unroll
            for (int w = 11; w < 32; ++w) r[w] = 0.f;
#pragma unroll
            for (int c = 0; c < 4; ++c) {
                bf16x8 v;
#pragma unroll
                for (int e = 0; e < 8; ++e) v[e] = (short)f2bf(r[c * 8 + e]);
                *(bf16x8*)(w1p + (size_t)k * 32 + (size_t)((c ^ (k & 3)) * 8)) = v;
            }
        }
        return;
    }

    // --- q compute: block (bid-780) of 1024, 4 waves x 4 rows ---
    for (int i = tid; i < 10 * 768; i += 256) wms[i] = wm[i];
    __syncthreads();

    const int wv = tid >> 6, l = tid & 63;
    const int mbase = (bid - 780) * 16 + wv * 4;
    const float thv = (l < 10) ? th[l] : 0.f;
    const float cth = __cosf(thv);

#pragma unroll
    for (int r = 0; r < 4; ++r) {
        const int m = mbase + r;
        const float4* xp = (const float4*)(x + (size_t)m * E_DIM);
        const float4 xa = xp[l], xb = xp[64 + l], xc = xp[128 + l];
        float s[10];
#pragma unroll
        for (int w = 0; w < 10; ++w) {
            const float4* wp = (const float4*)(wms + w * E_DIM);
            const float4 wa = wp[l], wb = wp[64 + l], wc = wp[128 + l];
            float t0 = xa.x * wa.x;
            float t1 = xa.y * wa.y;
            t0 = fmaf(xa.z, wa.z, t0); t1 = fmaf(xa.w, wa.w, t1);
            t0 = fmaf(xb.x, wb.x, t0); t1 = fmaf(xb.y, wb.y, t1);
            t0 = fmaf(xb.z, wb.z, t0); t1 = fmaf(xb.w, wb.w, t1);
            t0 = fmaf(xc.x, wc.x, t0); t1 = fmaf(xc.y, wc.y, t1);
            t0 = fmaf(xc.z, wc.z, t0); t1 = fmaf(xc.w, wc.w, t1);
            s[w] = t0 + t1;
        }
#pragma unroll
        for (int w = 0; w < 10; ++w) {
            float v = s[w];
            v += __shfl_xor(v, 1);  v += __shfl_xor(v, 2);  v += __shfl_xor(v, 4);
            v += __shfl_xor(v, 8);  v += __shfl_xor(v, 16); v += __shfl_xor(v, 32);
            s[w] = v;
        }
        if (l < 32) {
            float sv = 0.f;
#pragma unroll
            for (int w = 0; w < 10; ++w) sv = (l == w) ? s[w] : sv;
            float val = (l < 10) ? (cth * __cosf(sv)) : ((l == 10) ? 1.0f : 0.f);
            qp[(size_t)m * 32 + (size_t)((((l >> 3) ^ (m & 3)) * 8) + (l & 7))] = f2bf(val);
        }
    }
}

// ---------------- kG: pipelined fused h-compute + main GEMM (r7 + stagger) ----
// 512 blocks (128 m-tiles x 4 n-slabs), 512 threads (8 waves, 2m x 4n).
// BM=128, BN=192, BK=64. LDS = 2x24K (w2 dbuf) + 16K (h) = 64 KiB -> 2 blocks/CU.
__global__ __launch_bounds__(512, 4) void kG(const unsigned short* __restrict__ w2b,
                                             const float* __restrict__ b2,
                                             const unsigned short* __restrict__ qp,
                                             const unsigned short* __restrict__ w1p,
                                             float* __restrict__ outp) {
    __shared__ __align__(16) unsigned short w2s[2][192 * 64];  // 48 KB, [n][k] swz8
    __shared__ __align__(16) unsigned short hs[128 * 64];      // 16 KB, [m][k] swz8

    const int tid = (int)threadIdx.x;
    const int wv = tid >> 6, l = tid & 63;
    const int bid = (int)blockIdx.x;
    const int x8 = bid & 7, yb = bid >> 3;          // 2 XCDs per n-slab
    const int m0 = ((x8 & 1) * 64 + yb) * 128;
    const int n0 = (x8 >> 1) * 192;

    const int rw = tid >> 3, cw = tid & 7;   // W2 staging row/chunk
    const int wr = wv >> 2, wc = wv & 3;     // main-phase wave tile (2m x 4n)
    const int par = wv & 1;                  // window-order parity (stagger)

    // h-write element offsets (swapped layout)
    int hwo[4];
    {
        const int hm = wv * 16 + (l & 15);
        const int kb = (l >> 4) * 4;
#pragma unroll
        for (int ki = 0; ki < 4; ++ki) {
            int k = ki * 16 + kb;
            int c = k >> 3;
            hwo[ki] = hm * 64 + ((c ^ (hm & 7)) * 8) + (k & 7);
        }
    }

#define STAGE(BUF, KT) do { int k0_ = (KT) * 64;                                   \
    _Pragma("unroll") for (int i_ = 0; i_ < 3; ++i_) {                             \
        int r_ = i_ * 64 + rw;                                                     \
        gload16(w2b + (size_t)(n0 + r_) * FFN + k0_ + (size_t)cw * 8,              \
                (unsigned short*)w2s[BUF] + i_ * 4096 + wv * 512); } } while (0)

#define LOADW1(D, KT, KI) do {                                                     \
    const unsigned short* a_ = w1p + (size_t)((KT) * 64 + (KI) * 16 + (l & 15)) * 32 \
                                   + (size_t)(((l >> 4) ^ (l & 3)) * 8);           \
    asm volatile("global_load_dwordx4 %0, %1, off" : "=v"(D) : "v"(a_)); } while (0)

    // ---- prologue: q frag + stage(0) + w1 frags(0), all under one vmcnt(0) ----
    bf16x8 aq;
    {
        const unsigned short* qa = qp + (size_t)(m0 + wv * 16 + (l & 15)) * 32
                                      + (size_t)(((l >> 4) ^ (l & 3)) * 8);
        asm volatile("global_load_dwordx4 %0, %1, off" : "=v"(aq) : "v"(qa));
    }
    bf16x8 f0, f1, f2, f3, g0, g1, g2, g3;
    STAGE(0, 0);
    LOADW1(f0, 0, 0); LOADW1(f1, 0, 1); LOADW1(f2, 0, 2); LOADW1(f3, 0, 3);

    const f32x4 z4 = {0.f, 0.f, 0.f, 0.f};
    f32x4 acc[4][3];
#pragma unroll
    for (int a = 0; a < 4; ++a)
#pragma unroll
        for (int b = 0; b < 3; ++b) acc[a][b] = z4;

    int cur = 0;
    for (int t = 0; t < 48; ++t) {
        // B1: step t's loads (issued during t-1) done; prior hs/w2s readers done.
        asm volatile("s_waitcnt vmcnt(0)" ::: "memory");
        __builtin_amdgcn_sched_barrier(0);
        __builtin_amdgcn_s_barrier();
        __builtin_amdgcn_sched_barrier(0);

        if (t < 47) {   // issue step t+1 loads; they fly under h+main of step t
            STAGE(cur ^ 1, t + 1);
            LOADW1(g0, t + 1, 0); LOADW1(g1, t + 1, 1);
            LOADW1(g2, t + 1, 2); LOADW1(g3, t + 1, 3);
        }

        // ---- h phase (swapped): mfma(W1,q) -> lane l holds h[m=l&15][4 consecutive k]
        {
            f32x4 hv0 = __builtin_amdgcn_mfma_f32_16x16x32_bf16(f0, aq, z4, 0, 0, 0);
            f32x4 hv1 = __builtin_amdgcn_mfma_f32_16x16x32_bf16(f1, aq, z4, 0, 0, 0);
            f32x4 hv2 = __builtin_amdgcn_mfma_f32_16x16x32_bf16(f2, aq, z4, 0, 0, 0);
            f32x4 hv3 = __builtin_amdgcn_mfma_f32_16x16x32_bf16(f3, aq, z4, 0, 0, 0);
            uint2 pw;
            pw.x = pkbf(fmaxf(hv0[0], 0.f), fmaxf(hv0[1], 0.f));
            pw.y = pkbf(fmaxf(hv0[2], 0.f), fmaxf(hv0[3], 0.f));
            *(uint2*)(hs + hwo[0]) = pw;
            pw.x = pkbf(fmaxf(hv1[0], 0.f), fmaxf(hv1[1], 0.f));
            pw.y = pkbf(fmaxf(hv1[2], 0.f), fmaxf(hv1[3], 0.f));
            *(uint2*)(hs + hwo[1]) = pw;
            pw.x = pkbf(fmaxf(hv2[0], 0.f), fmaxf(hv2[1], 0.f));
            pw.y = pkbf(fmaxf(hv2[2], 0.f), fmaxf(hv2[3], 0.f));
            *(uint2*)(hs + hwo[2]) = pw;
            pw.x = pkbf(fmaxf(hv3[0], 0.f), fmaxf(hv3[1], 0.f));
            pw.y = pkbf(fmaxf(hv3[2], 0.f), fmaxf(hv3[3], 0.f));
            *(uint2*)(hs + hwo[3]) = pw;
        }

        // B2: hs writes visible to all waves (LDS-only drain; VMEM flies through).
        asm volatile("s_waitcnt lgkmcnt(0)" ::: "memory");
        __builtin_amdgcn_sched_barrier(0);
        __builtin_amdgcn_s_barrier();
        __builtin_amdgcn_sched_barrier(0);

        // ---- main phase: acc += h @ W2tile^T, wave-staggered window order ----
        {
            const unsigned short* w2c = (const unsigned short*)w2s[cur];
#pragma unroll
            for (int kx = 0; kx < 2; ++kx) {
                const int win = kx ^ par;            // stagger: halves LDS burst
                const int kc = win * 4 + (l >> 4);
                bf16x8 af[4], bfr[3];
#pragma unroll
                for (int mi = 0; mi < 4; ++mi) {
                    int m_ = wr * 64 + mi * 16 + (l & 15);
                    af[mi] = *(const bf16x8*)(hs + m_ * 64 + ((kc ^ (m_ & 7)) * 8));
                }
#pragma unroll
                for (int ni = 0; ni < 3; ++ni) {
                    int n_ = wc * 48 + ni * 16 + (l & 15);
                    bfr[ni] = *(const bf16x8*)(w2c + n_ * 64 + ((kc ^ (n_ & 7)) * 8));
                }
                __builtin_amdgcn_s_setprio(1);
#pragma unroll
                for (int ni = 0; ni < 3; ++ni)
#pragma unroll
                    for (int mi = 0; mi < 4; ++mi)
                        acc[mi][ni] = __builtin_amdgcn_mfma_f32_16x16x32_bf16(af[mi], bfr[ni], acc[mi][ni], 0, 0, 0);
                __builtin_amdgcn_s_setprio(0);
            }
        }

        f0 = g0; f1 = g1; f2 = g2; f3 = g3;
        cur ^= 1;
    }
#undef STAGE
#undef LOADW1

    // epilogue: + b2, fp32 store
#pragma unroll
    for (int ni = 0; ni < 3; ++ni) {
        int n = n0 + wc * 48 + ni * 16 + (l & 15);
        float b2v = b2[n];
#pragma unroll
        for (int mi = 0; mi < 4; ++mi) {
            int mb = m0 + wr * 64 + mi * 16 + (l >> 4) * 4;
#pragma unroll
            for (int jj = 0; jj < 4; ++jj)
                outp[(size_t)(mb + jj) * E_DIM + n] = acc[mi][ni][jj] + b2v;
        }
    }
}

extern "C" void kernel_launch(void* const* d_in, const int* in_sizes, int n_in,
                              void* d_out, int out_size, void* d_ws, size_t ws_size,
                              hipStream_t stream) {
    const float* x    = (const float*)d_in[0];
    const float* wmap = (const float*)d_in[1];
    const float* th   = (const float*)d_in[2];
    const float* w1   = (const float*)d_in[3];
    const float* b1   = (const float*)d_in[4];
    const float* w2   = (const float*)d_in[5];
    const float* b2   = (const float*)d_in[6];
    float* out = (float*)d_out;

    unsigned short* qp  = (unsigned short*)d_ws;            // 16384*32 bf16 = 1 MiB
    unsigned short* w1p = qp + (size_t)F_TOTAL * 32;        // 3072*32 bf16 = 192 KiB
    unsigned short* w2b = w1p + (size_t)FFN * 32;           // 768*3072 bf16 = 4.5 MiB

    kPre<<<1804, 256, 0, stream>>>(x, wmap, th, w1, b1, w2, w2b, w1p, qp);
    kG<<<512, 512, 0, stream>>>(w2b, b2, qp, w1p, out);
}